// Round 13
// baseline (63.811 us; speedup 1.0000x reference)
//
#include <hip/hip_runtime.h>
#include <stdint.h>

// Problem constants
#define M_ROWS   16000        // B*T
#define D_IN     320
#define E_DIM    16
#define K_CB     8192
#define NCHUNK   64           // half-chunks: 8 k-tiles (128 codewords) each
#define KT_PER_CHUNK 8
#define RPT      2            // row-tiles per wave per group
#define NGRP     2            // row-groups per block (reuse staged LDS)
#define NRB      63           // row-blocks (16 rt each: 4 waves x RPT x NGRP)

typedef __attribute__((ext_vector_type(8))) short bf16x8;
typedef __attribute__((ext_vector_type(4))) float f32x4;

// Workspace layout (bytes)
#define XA_OFF   0u                       // [1008 tiles][64 lanes][8 bf16]  (h|m)
#define XB_OFF   1032192u                 // same shape                       (l|h)
#define CBA_OFF  2064384u                 // [512 ktiles][64 lanes][8 bf16]  (h'|m')
#define CBC_OFF  2588672u                 // same                             (h'|l')
#define PART_OFF 3112960u                 // [16000 rows][64 kc] u64 partials

#define AS1 __attribute__((address_space(1)))
#define AS3 __attribute__((address_space(3)))

__device__ __forceinline__ unsigned short f2bf(float x) {
    union { float f; unsigned u; } v; v.f = x;
    unsigned r = v.u + 0x7FFFu + ((v.u >> 16) & 1u);   // round-to-nearest-even
    return (unsigned short)(r >> 16);
}
__device__ __forceinline__ float bf2f(unsigned short b) {
    union { unsigned u; float f; } v; v.u = ((unsigned)b) << 16; return v.f;
}

// ---------- Fused prep: projection-split-pack (blocks 0..249) + codebook
// split-pack (blocks 250..377). Byte-identical to round 10. ----------
__global__ __launch_bounds__(256) void prep_kernel(const float* __restrict__ hs,
                                                   const float* __restrict__ P,
                                                   const float* __restrict__ CB,
                                                   unsigned short* __restrict__ Xa,
                                                   unsigned short* __restrict__ Xb,
                                                   unsigned short* __restrict__ CBa,
                                                   unsigned short* __restrict__ CBc) {
    int bid = blockIdx.x;
    int t   = threadIdx.x;
    if (bid < 250) {
        int row = bid * 64 + (t >> 2);
        int eq  = t & 3;
        if (row >= M_ROWS) return;
        const float* hrow = hs + (size_t)row * D_IN;
        float ax = 0.f, ay = 0.f, az = 0.f, aw = 0.f;
        #pragma unroll 4
        for (int d = 0; d < D_IN; d += 4) {
            float4 h4 = *reinterpret_cast<const float4*>(hrow + d);
            float4 p0 = *reinterpret_cast<const float4*>(P + (size_t)(d + 0) * E_DIM + eq * 4);
            float4 p1 = *reinterpret_cast<const float4*>(P + (size_t)(d + 1) * E_DIM + eq * 4);
            float4 p2 = *reinterpret_cast<const float4*>(P + (size_t)(d + 2) * E_DIM + eq * 4);
            float4 p3 = *reinterpret_cast<const float4*>(P + (size_t)(d + 3) * E_DIM + eq * 4);
            ax += h4.x * p0.x + h4.y * p1.x + h4.z * p2.x + h4.w * p3.x;
            ay += h4.x * p0.y + h4.y * p1.y + h4.z * p2.y + h4.w * p3.y;
            az += h4.x * p0.z + h4.y * p1.z + h4.z * p2.z + h4.w * p3.z;
            aw += h4.x * p0.w + h4.y * p1.w + h4.z * p2.w + h4.w * p3.w;
        }
        float v[4] = {ax, ay, az, aw};
        ushort4 h, m, l;
        unsigned short* hp = (unsigned short*)&h;
        unsigned short* mp = (unsigned short*)&m;
        unsigned short* lp = (unsigned short*)&l;
        #pragma unroll
        for (int i = 0; i < 4; ++i) {
            unsigned short hb = f2bf(v[i]);      float r1 = v[i] - bf2f(hb);
            unsigned short mb = f2bf(r1);        float r2 = r1 - bf2f(mb);
            unsigned short lb = f2bf(r2);        // exact: v = h + m + l
            hp[i] = hb; mp[i] = mb; lp[i] = lb;
        }
        int rt = row >> 4, rl = row & 15;
        int g  = eq >> 1;
        int j0 = (eq & 1) * 4;
        size_t base = (size_t)rt * 512;
        *reinterpret_cast<ushort4*>(Xa + base + ((g    ) * 16 + rl) * 8 + j0) = h;
        *reinterpret_cast<ushort4*>(Xa + base + ((2 + g) * 16 + rl) * 8 + j0) = m;
        *reinterpret_cast<ushort4*>(Xb + base + ((g    ) * 16 + rl) * 8 + j0) = l;
        *reinterpret_cast<ushort4*>(Xb + base + ((2 + g) * 16 + rl) * 8 + j0) = h;
    } else {
        int bid2 = bid - 250;                     // 0..127
        int c  = bid2 * 64 + (t >> 2);
        int eq = t & 3;
        float4 v4 = *reinterpret_cast<const float4*>(CB + (size_t)c * E_DIM + eq * 4);
        float v[4] = {v4.x, v4.y, v4.z, v4.w};
        ushort4 h, m, l;
        unsigned short* hp = (unsigned short*)&h;
        unsigned short* mp = (unsigned short*)&m;
        unsigned short* lp = (unsigned short*)&l;
        #pragma unroll
        for (int i = 0; i < 4; ++i) {
            unsigned short hb = f2bf(v[i]);      float r1 = v[i] - bf2f(hb);
            unsigned short mb = f2bf(r1);        float r2 = r1 - bf2f(mb);
            unsigned short lb = f2bf(r2);
            hp[i] = hb; mp[i] = mb; lp[i] = lb;
        }
        int kt = c >> 4, cl = c & 15;
        int g  = eq >> 1;
        int j0 = (eq & 1) * 4;
        size_t base = (size_t)kt * 512;
        *reinterpret_cast<ushort4*>(CBa + base + ((g    ) * 16 + cl) * 8 + j0) = h;
        *reinterpret_cast<ushort4*>(CBa + base + ((2 + g) * 16 + cl) * 8 + j0) = m;
        *reinterpret_cast<ushort4*>(CBc + base + ((g    ) * 16 + cl) * 8 + j0) = h;
        *reinterpret_cast<ushort4*>(CBc + base + ((2 + g) * 16 + cl) * 8 + j0) = l;
    }
}

// ---------- MFMA score + fused argmax; low-VGPR / high-occupancy config ----------
// 4032 blocks x 256 threads (4 waves). Half-chunk (8 kt) of both B streams in
// 16 KB LDS via global_load_lds; ONE barrier; barrier-free inner loop. RPT=2
// keeps live VGPR < 64 -> __launch_bounds__(256,8) -> 8 waves/SIMD resident.
// NGRP=2 row-groups reuse the staged chunk. Exact 3-MFMA fp32-split scores;
// strict-gt argmax; u64-key shfl reduce; plain store to part[row][kc].
__global__ __launch_bounds__(256, 8) void score_kernel(const unsigned short* __restrict__ Xa,
                                                       const unsigned short* __restrict__ Xb,
                                                       const unsigned short* __restrict__ CBa,
                                                       const unsigned short* __restrict__ CBc,
                                                       unsigned long long* __restrict__ part) {
    __shared__ unsigned short sA[KT_PER_CHUNK * 512];   // 8 KB  (h'|m')
    __shared__ unsigned short sC[KT_PER_CHUNK * 512];   // 8 KB  (h'|l')

    int t    = threadIdx.x;
    int lane = t & 63;
    int w    = t >> 6;                // 0..3
    int flat = blockIdx.x;            // 0..4031
    int xcd  = flat & 7;
    int idx  = flat >> 3;             // 0..503
    int kc   = xcd * 8 + idx / NRB;   // 0..63, clustered per XCD
    int rb   = idx % NRB;             // 0..62

    // Stage both B half-chunk streams (8 KB each, 2 glds rounds each).
    {
        const unsigned char* ga = (const unsigned char*)(CBa + (size_t)kc * KT_PER_CHUNK * 512);
        const unsigned char* gc = (const unsigned char*)(CBc + (size_t)kc * KT_PER_CHUNK * 512);
        unsigned char* la = (unsigned char*)sA;
        unsigned char* lc = (unsigned char*)sC;
        int wo = w * 1024 + lane * 16;
        #pragma unroll
        for (int q = 0; q < 2; ++q)
            __builtin_amdgcn_global_load_lds((const AS1 void*)(ga + q * 4096 + wo),
                                             (AS3 void*)(la + q * 4096 + w * 1024), 16, 0, 0);
        #pragma unroll
        for (int q = 0; q < 2; ++q)
            __builtin_amdgcn_global_load_lds((const AS1 void*)(gc + q * 4096 + wo),
                                             (AS3 void*)(lc + q * 4096 + w * 1024), 16, 0, 0);
    }

    __syncthreads();   // compiler emits vmcnt(0) drain: staging complete

    const bf16x8* sA8 = reinterpret_cast<const bf16x8*>(sA);
    const bf16x8* sC8 = reinterpret_cast<const bf16x8*>(sC);
    int lsw  = lane ^ 32;             // swapped-half lane for the [m'|h'] operand
    int colc = lane & 15;

    #pragma unroll
    for (int g = 0; g < NGRP; ++g) {
        int rt0 = rb * 16 + g * 8 + w * RPT;

        bf16x8 a_hm[RPT], a_lh[RPT];
        #pragma unroll
        for (int r = 0; r < RPT; ++r) {
            a_hm[r] = *reinterpret_cast<const bf16x8*>(Xa + ((size_t)(rt0 + r) * 64 + lane) * 8);
            a_lh[r] = *reinterpret_cast<const bf16x8*>(Xb + ((size_t)(rt0 + r) * 64 + lane) * 8);
        }
        float best[RPT][4];
        int   bidx[RPT][4];
        #pragma unroll
        for (int r = 0; r < RPT; ++r)
            #pragma unroll
            for (int i = 0; i < 4; ++i) { best[r][i] = -3.0e38f; bidx[r][i] = 0; }

        #pragma unroll 2
        for (int kt = 0; kt < KT_PER_CHUNK; ++kt) {
            bf16x8 c1 = sA8[kt * 64 + lane];
            bf16x8 c2 = sA8[kt * 64 + lsw];
            bf16x8 c3 = sC8[kt * 64 + lane];
            #pragma unroll
            for (int r = 0; r < RPT; ++r) {
                f32x4 acc = {0.f, 0.f, 0.f, 0.f};
                acc = __builtin_amdgcn_mfma_f32_16x16x32_bf16(a_hm[r], c1, acc, 0, 0, 0); // hh+mm
                acc = __builtin_amdgcn_mfma_f32_16x16x32_bf16(a_hm[r], c2, acc, 0, 0, 0); // hm+mh
                acc = __builtin_amdgcn_mfma_f32_16x16x32_bf16(a_lh[r], c3, acc, 0, 0, 0); // lh+hl
                #pragma unroll
                for (int i = 0; i < 4; ++i) {
                    bool gt = acc[i] > best[r][i];
                    best[r][i] = gt ? acc[i] : best[r][i];
                    bidx[r][i] = gt ? kt     : bidx[r][i];
                }
            }
        }

        // u64-key shfl reduce over the 16 columns; 1 store per row.
        // Key = mono(score)<<32 | ~idx (verified round-2 semantics).
        #pragma unroll
        for (int r = 0; r < RPT; ++r) {
            #pragma unroll
            for (int i = 0; i < 4; ++i) {
                unsigned u    = __float_as_uint(best[r][i]);
                unsigned mono = (u & 0x80000000u) ? ~u : (u | 0x80000000u);
                unsigned kg   = (unsigned)(kc * 128 + bidx[r][i] * 16 + colc);
                unsigned long long key = ((unsigned long long)mono << 32) | (unsigned)(~kg);
                #pragma unroll
                for (int off = 1; off <= 8; off <<= 1) {
                    unsigned long long ok =
                        (((unsigned long long)(unsigned)__shfl_xor((int)(key >> 32), off, 64)) << 32) |
                        (unsigned)__shfl_xor((int)(unsigned)key, off, 64);
                    key = (ok > key) ? ok : key;
                }
                if (colc == 0) {
                    int row = (rt0 + r) * 16 + (lane >> 4) * 4 + i;
                    if (row < M_ROWS) part[(size_t)row * NCHUNK + kc] = key;
                }
            }
        }
    }
}

// ---------- Decode: reduce 64 per-chunk keys per row -> int32 index ----------
// Block = 256 thr = 4 waves; wave handles 4 rows (16 lanes/row, 4 u64 each).
__global__ __launch_bounds__(256) void decode_kernel(const unsigned long long* __restrict__ part,
                                                     int* __restrict__ out) {
    int t    = threadIdx.x;
    int lane = t & 63;
    int wv   = t >> 6;
    int row  = blockIdx.x * 16 + wv * 4 + (lane >> 4);
    int j    = lane & 15;
    const unsigned long long* p = part + (size_t)row * NCHUNK + j * 4;
    unsigned long long k0 = p[0], k1 = p[1], k2 = p[2], k3 = p[3];
    k0 = k0 > k1 ? k0 : k1;
    k2 = k2 > k3 ? k2 : k3;
    unsigned long long key = k0 > k2 ? k0 : k2;
    #pragma unroll
    for (int off = 1; off <= 8; off <<= 1) {
        unsigned long long ok =
            (((unsigned long long)(unsigned)__shfl_xor((int)(key >> 32), off, 64)) << 32) |
            (unsigned)__shfl_xor((int)(unsigned)key, off, 64);
        key = (ok > key) ? ok : key;
    }
    if (j == 0) out[row] = (int)(~(unsigned)(key & 0xFFFFFFFFull));
}

extern "C" void kernel_launch(void* const* d_in, const int* in_sizes, int n_in,
                              void* d_out, int out_size, void* d_ws, size_t ws_size,
                              hipStream_t stream) {
    const float* hs = (const float*)d_in[0];   // [8,2000,320]
    const float* P  = (const float*)d_in[1];   // [1,320,16]
    const float* CB = (const float*)d_in[2];   // [1,8192,16]
    int* out = (int*)d_out;                    // [8,1,2000] int32

    char* ws = (char*)d_ws;
    unsigned short* Xa  = (unsigned short*)(ws + XA_OFF);
    unsigned short* Xb  = (unsigned short*)(ws + XB_OFF);
    unsigned short* CBa = (unsigned short*)(ws + CBA_OFF);
    unsigned short* CBc = (unsigned short*)(ws + CBC_OFF);
    unsigned long long* part = (unsigned long long*)(ws + PART_OFF);

    prep_kernel<<<dim3(378), dim3(256), 0, stream>>>(hs, P, CB, Xa, Xb, CBa, CBc);
    score_kernel<<<dim3(NRB * NCHUNK), dim3(256), 0, stream>>>(Xa, Xb, CBa, CBc, part);
    decode_kernel<<<dim3(M_ROWS / 16), dim3(256), 0, stream>>>(part, out);
}

// Round 14
// 57.278 us; speedup vs baseline: 1.1140x; 1.1140x over previous
//
#include <hip/hip_runtime.h>
#include <stdint.h>

// Problem constants
#define M_ROWS   16000        // B*T
#define D_IN     320
#define E_DIM    16
#define K_CB     8192
#define NCHUNK   32           // k-chunks: 16 k-tiles (256 codewords) each
#define KT_PER_CHUNK 16
#define RPT      2            // row-tiles per wave per group
#define NGRP     2            // row-groups per block (reuse staged LDS)
#define NRB      64           // row-blocks (16 rt each; rb=63 is dummy padding)

typedef __attribute__((ext_vector_type(8))) short bf16x8;
typedef __attribute__((ext_vector_type(4))) float f32x4;

// Workspace layout (bytes) — XA/XB padded to 1024 tiles for the dummy rb
#define XA_OFF   0u                       // [1024 tiles][64 lanes][8 bf16]  (h|m)
#define XB_OFF   1048576u                 // same shape                       (l|h)
#define CBA_OFF  2097152u                 // [512 ktiles][64 lanes][8 bf16]  (h'|m')
#define CBC_OFF  2621440u                 // same                             (h'|l')
#define PART_OFF 3145728u                 // [16000 rows][32 kc] u64 partials

#define AS1 __attribute__((address_space(1)))
#define AS3 __attribute__((address_space(3)))

__device__ __forceinline__ unsigned short f2bf(float x) {
    union { float f; unsigned u; } v; v.f = x;
    unsigned r = v.u + 0x7FFFu + ((v.u >> 16) & 1u);   // round-to-nearest-even
    return (unsigned short)(r >> 16);
}
__device__ __forceinline__ float bf2f(unsigned short b) {
    union { unsigned u; float f; } v; v.u = ((unsigned)b) << 16; return v.f;
}

// ---------- Fused prep: projection-split-pack (blocks 0..249) + codebook
// split-pack (blocks 250..377). Math byte-identical to rounds 2-13. ----------
__global__ __launch_bounds__(256) void prep_kernel(const float* __restrict__ hs,
                                                   const float* __restrict__ P,
                                                   const float* __restrict__ CB,
                                                   unsigned short* __restrict__ Xa,
                                                   unsigned short* __restrict__ Xb,
                                                   unsigned short* __restrict__ CBa,
                                                   unsigned short* __restrict__ CBc) {
    int bid = blockIdx.x;
    int t   = threadIdx.x;
    if (bid < 250) {
        int row = bid * 64 + (t >> 2);
        int eq  = t & 3;
        if (row >= M_ROWS) return;
        const float* hrow = hs + (size_t)row * D_IN;
        float ax = 0.f, ay = 0.f, az = 0.f, aw = 0.f;
        #pragma unroll 4
        for (int d = 0; d < D_IN; d += 4) {
            float4 h4 = *reinterpret_cast<const float4*>(hrow + d);
            float4 p0 = *reinterpret_cast<const float4*>(P + (size_t)(d + 0) * E_DIM + eq * 4);
            float4 p1 = *reinterpret_cast<const float4*>(P + (size_t)(d + 1) * E_DIM + eq * 4);
            float4 p2 = *reinterpret_cast<const float4*>(P + (size_t)(d + 2) * E_DIM + eq * 4);
            float4 p3 = *reinterpret_cast<const float4*>(P + (size_t)(d + 3) * E_DIM + eq * 4);
            ax += h4.x * p0.x + h4.y * p1.x + h4.z * p2.x + h4.w * p3.x;
            ay += h4.x * p0.y + h4.y * p1.y + h4.z * p2.y + h4.w * p3.y;
            az += h4.x * p0.z + h4.y * p1.z + h4.z * p2.z + h4.w * p3.z;
            aw += h4.x * p0.w + h4.y * p1.w + h4.z * p2.w + h4.w * p3.w;
        }
        float v[4] = {ax, ay, az, aw};
        ushort4 h, m, l;
        unsigned short* hp = (unsigned short*)&h;
        unsigned short* mp = (unsigned short*)&m;
        unsigned short* lp = (unsigned short*)&l;
        #pragma unroll
        for (int i = 0; i < 4; ++i) {
            unsigned short hb = f2bf(v[i]);      float r1 = v[i] - bf2f(hb);
            unsigned short mb = f2bf(r1);        float r2 = r1 - bf2f(mb);
            unsigned short lb = f2bf(r2);        // exact: v = h + m + l
            hp[i] = hb; mp[i] = mb; lp[i] = lb;
        }
        int rt = row >> 4, rl = row & 15;
        int g  = eq >> 1;
        int j0 = (eq & 1) * 4;
        size_t base = (size_t)rt * 512;
        *reinterpret_cast<ushort4*>(Xa + base + ((g    ) * 16 + rl) * 8 + j0) = h;
        *reinterpret_cast<ushort4*>(Xa + base + ((2 + g) * 16 + rl) * 8 + j0) = m;
        *reinterpret_cast<ushort4*>(Xb + base + ((g    ) * 16 + rl) * 8 + j0) = l;
        *reinterpret_cast<ushort4*>(Xb + base + ((2 + g) * 16 + rl) * 8 + j0) = h;
    } else {
        int bid2 = bid - 250;                     // 0..127
        int c  = bid2 * 64 + (t >> 2);
        int eq = t & 3;
        float4 v4 = *reinterpret_cast<const float4*>(CB + (size_t)c * E_DIM + eq * 4);
        float v[4] = {v4.x, v4.y, v4.z, v4.w};
        ushort4 h, m, l;
        unsigned short* hp = (unsigned short*)&h;
        unsigned short* mp = (unsigned short*)&m;
        unsigned short* lp = (unsigned short*)&l;
        #pragma unroll
        for (int i = 0; i < 4; ++i) {
            unsigned short hb = f2bf(v[i]);      float r1 = v[i] - bf2f(hb);
            unsigned short mb = f2bf(r1);        float r2 = r1 - bf2f(mb);
            unsigned short lb = f2bf(r2);
            hp[i] = hb; mp[i] = mb; lp[i] = lb;
        }
        int kt = c >> 4, cl = c & 15;
        int g  = eq >> 1;
        int j0 = (eq & 1) * 4;
        size_t base = (size_t)kt * 512;
        *reinterpret_cast<ushort4*>(CBa + base + ((g    ) * 16 + cl) * 8 + j0) = h;
        *reinterpret_cast<ushort4*>(CBa + base + ((2 + g) * 16 + cl) * 8 + j0) = m;
        *reinterpret_cast<ushort4*>(CBc + base + ((g    ) * 16 + cl) * 8 + j0) = h;
        *reinterpret_cast<ushort4*>(CBc + base + ((2 + g) * 16 + cl) * 8 + j0) = l;
    }
}

// ---------- MFMA score + fused argmax ----------
// 2048 blocks x 256 threads (4 waves). rb-clustered XCD swizzle: xcd=bid&7
// owns rb in {xcd, xcd+8, ...} so each XCD's A-fragment slice (256 KB) + the
// full CB fragments (1 MB) stay L2-resident. Whole 16-kt chunk of both B
// streams staged in 32 KB LDS via global_load_lds; ONE barrier; barrier-free
// inner loop. RPT=2 x NGRP=2 keeps live VGPR < 64 (round-13-proven) ->
// (256,8). Exact 3-MFMA fp32-split scores; strict-gt argmax; u64-key shfl
// reduce (verified round-2 semantics); plain store to part[row][kc].
__global__ __launch_bounds__(256, 8) void score_kernel(const unsigned short* __restrict__ Xa,
                                                       const unsigned short* __restrict__ Xb,
                                                       const unsigned short* __restrict__ CBa,
                                                       const unsigned short* __restrict__ CBc,
                                                       unsigned long long* __restrict__ part) {
    __shared__ unsigned short sA[KT_PER_CHUNK * 512];   // 16 KB  (h'|m')
    __shared__ unsigned short sC[KT_PER_CHUNK * 512];   // 16 KB  (h'|l')

    int t    = threadIdx.x;
    int lane = t & 63;
    int w    = t >> 6;                // 0..3
    int bid  = blockIdx.x;            // 0..2047
    int xcd  = bid & 7;
    int idx  = bid >> 3;              // 0..255
    int j    = idx & 7;
    int kc   = idx >> 3;              // 0..31
    int rb   = xcd + 8 * j;           // 0..63 (rb=63 dummy), clustered per XCD

    // Stage both B streams for the whole k-chunk (4 glds rounds each).
    {
        const unsigned char* ga = (const unsigned char*)(CBa + (size_t)kc * KT_PER_CHUNK * 512);
        const unsigned char* gc = (const unsigned char*)(CBc + (size_t)kc * KT_PER_CHUNK * 512);
        unsigned char* la = (unsigned char*)sA;
        unsigned char* lc = (unsigned char*)sC;
        int wo = w * 1024 + lane * 16;
        #pragma unroll
        for (int q = 0; q < 4; ++q)
            __builtin_amdgcn_global_load_lds((const AS1 void*)(ga + q * 4096 + wo),
                                             (AS3 void*)(la + q * 4096 + w * 1024), 16, 0, 0);
        #pragma unroll
        for (int q = 0; q < 4; ++q)
            __builtin_amdgcn_global_load_lds((const AS1 void*)(gc + q * 4096 + wo),
                                             (AS3 void*)(lc + q * 4096 + w * 1024), 16, 0, 0);
    }

    __syncthreads();   // compiler emits vmcnt(0) drain: staging complete

    const bf16x8* sA8 = reinterpret_cast<const bf16x8*>(sA);
    const bf16x8* sC8 = reinterpret_cast<const bf16x8*>(sC);
    int lsw  = lane ^ 32;             // swapped-half lane for the [m'|h'] operand
    int colc = lane & 15;

    #pragma unroll
    for (int g = 0; g < NGRP; ++g) {
        int rt0 = rb * 16 + g * 8 + w * RPT;

        bf16x8 a_hm[RPT], a_lh[RPT];
        #pragma unroll
        for (int r = 0; r < RPT; ++r) {
            a_hm[r] = *reinterpret_cast<const bf16x8*>(Xa + ((size_t)(rt0 + r) * 64 + lane) * 8);
            a_lh[r] = *reinterpret_cast<const bf16x8*>(Xb + ((size_t)(rt0 + r) * 64 + lane) * 8);
        }
        float best[RPT][4];
        int   bidx[RPT][4];
        #pragma unroll
        for (int r = 0; r < RPT; ++r)
            #pragma unroll
            for (int i = 0; i < 4; ++i) { best[r][i] = -3.0e38f; bidx[r][i] = 0; }

        #pragma unroll 2
        for (int kt = 0; kt < KT_PER_CHUNK; ++kt) {
            bf16x8 c1 = sA8[kt * 64 + lane];
            bf16x8 c2 = sA8[kt * 64 + lsw];
            bf16x8 c3 = sC8[kt * 64 + lane];
            #pragma unroll
            for (int r = 0; r < RPT; ++r) {
                f32x4 acc = {0.f, 0.f, 0.f, 0.f};
                acc = __builtin_amdgcn_mfma_f32_16x16x32_bf16(a_hm[r], c1, acc, 0, 0, 0); // hh+mm
                acc = __builtin_amdgcn_mfma_f32_16x16x32_bf16(a_hm[r], c2, acc, 0, 0, 0); // hm+mh
                acc = __builtin_amdgcn_mfma_f32_16x16x32_bf16(a_lh[r], c3, acc, 0, 0, 0); // lh+hl
                #pragma unroll
                for (int i = 0; i < 4; ++i) {
                    bool gt = acc[i] > best[r][i];
                    best[r][i] = gt ? acc[i] : best[r][i];
                    bidx[r][i] = gt ? kt     : bidx[r][i];
                }
            }
        }

        // u64-key shfl reduce over the 16 columns; 1 store per row.
        #pragma unroll
        for (int r = 0; r < RPT; ++r) {
            #pragma unroll
            for (int i = 0; i < 4; ++i) {
                unsigned u    = __float_as_uint(best[r][i]);
                unsigned mono = (u & 0x80000000u) ? ~u : (u | 0x80000000u);
                unsigned kg   = (unsigned)(kc * 256 + bidx[r][i] * 16 + colc);
                unsigned long long key = ((unsigned long long)mono << 32) | (unsigned)(~kg);
                #pragma unroll
                for (int off = 1; off <= 8; off <<= 1) {
                    unsigned long long ok =
                        (((unsigned long long)(unsigned)__shfl_xor((int)(key >> 32), off, 64)) << 32) |
                        (unsigned)__shfl_xor((int)(unsigned)key, off, 64);
                    key = (ok > key) ? ok : key;
                }
                if (colc == 0) {
                    int row = (rt0 + r) * 16 + (lane >> 4) * 4 + i;
                    if (row < M_ROWS) part[(size_t)row * NCHUNK + kc] = key;
                }
            }
        }
    }
}

// ---------- Decode: reduce 32 per-chunk keys per row -> int32 index ----------
__global__ __launch_bounds__(256) void decode_kernel(const unsigned long long* __restrict__ part,
                                                     int* __restrict__ out) {
    int t    = threadIdx.x;
    int lane = t & 63;
    int wv   = t >> 6;
    int row  = blockIdx.x * 32 + wv * 8 + (lane >> 3);
    int j    = lane & 7;
    const unsigned long long* p = part + (size_t)row * NCHUNK + j * 4;
    unsigned long long k0 = p[0], k1 = p[1], k2 = p[2], k3 = p[3];
    k0 = k0 > k1 ? k0 : k1;
    k2 = k2 > k3 ? k2 : k3;
    unsigned long long key = k0 > k2 ? k0 : k2;
    #pragma unroll
    for (int off = 1; off <= 4; off <<= 1) {
        unsigned long long ok =
            (((unsigned long long)(unsigned)__shfl_xor((int)(key >> 32), off, 64)) << 32) |
            (unsigned)__shfl_xor((int)(unsigned)key, off, 64);
        key = (ok > key) ? ok : key;
    }
    if (j == 0) out[row] = (int)(~(unsigned)(key & 0xFFFFFFFFull));
}

extern "C" void kernel_launch(void* const* d_in, const int* in_sizes, int n_in,
                              void* d_out, int out_size, void* d_ws, size_t ws_size,
                              hipStream_t stream) {
    const float* hs = (const float*)d_in[0];   // [8,2000,320]
    const float* P  = (const float*)d_in[1];   // [1,320,16]
    const float* CB = (const float*)d_in[2];   // [1,8192,16]
    int* out = (int*)d_out;                    // [8,1,2000] int32

    char* ws = (char*)d_ws;
    unsigned short* Xa  = (unsigned short*)(ws + XA_OFF);
    unsigned short* Xb  = (unsigned short*)(ws + XB_OFF);
    unsigned short* CBa = (unsigned short*)(ws + CBA_OFF);
    unsigned short* CBc = (unsigned short*)(ws + CBC_OFF);
    unsigned long long* part = (unsigned long long*)(ws + PART_OFF);

    prep_kernel<<<dim3(378), dim3(256), 0, stream>>>(hs, P, CB, Xa, Xb, CBa, CBc);
    score_kernel<<<dim3(NRB * NCHUNK), dim3(256), 0, stream>>>(Xa, Xb, CBa, CBc, part);
    decode_kernel<<<dim3(M_ROWS / 32), dim3(256), 0, stream>>>(part, out);
}

// Round 16
// 56.355 us; speedup vs baseline: 1.1323x; 1.0164x over previous
//
#include <hip/hip_runtime.h>
#include <stdint.h>

// Problem constants
#define M_ROWS   16000        // B*T
#define D_IN     320
#define E_DIM    16
#define K_CB     8192
#define NCHUNK   32           // k-chunks: 16 k-tiles (256 codewords) each
#define KT_PER_CHUNK 16
#define RPT      2            // row-tiles per wave per group
#define NGRP     2            // row-groups per block (reuse staged LDS)
#define NRB      64           // row-blocks (16 rt each; rb=63 is dummy padding)

typedef __attribute__((ext_vector_type(8))) short bf16x8;
typedef __attribute__((ext_vector_type(4))) float f32x4;

// Workspace layout (bytes) — XA/XB padded to 1024 tiles for the dummy rb
#define XA_OFF   0u                       // [1024 tiles][64 lanes][8 bf16]  (h|m)
#define XB_OFF   1048576u                 // same shape                       (l|h)
#define CBA_OFF  2097152u                 // [512 ktiles][64 lanes][8 bf16]  (h'|m')
#define CBC_OFF  2621440u                 // same                             (h'|l')
#define PART_OFF 3145728u                 // [16000 rows][32 kc] u64 partials

#define AS1 __attribute__((address_space(1)))
#define AS3 __attribute__((address_space(3)))

__device__ __forceinline__ unsigned short f2bf(float x) {
    union { float f; unsigned u; } v; v.f = x;
    unsigned r = v.u + 0x7FFFu + ((v.u >> 16) & 1u);   // round-to-nearest-even
    return (unsigned short)(r >> 16);
}
__device__ __forceinline__ float bf2f(unsigned short b) {
    union { unsigned u; float f; } v; v.u = ((unsigned)b) << 16; return v.f;
}

// ---------- Fused prep: projection-split-pack (blocks 0..249) + codebook
// split-pack (blocks 250..377). Byte-identical to round 14. ----------
__global__ __launch_bounds__(256) void prep_kernel(const float* __restrict__ hs,
                                                   const float* __restrict__ P,
                                                   const float* __restrict__ CB,
                                                   unsigned short* __restrict__ Xa,
                                                   unsigned short* __restrict__ Xb,
                                                   unsigned short* __restrict__ CBa,
                                                   unsigned short* __restrict__ CBc) {
    int bid = blockIdx.x;
    int t   = threadIdx.x;
    if (bid < 250) {
        int row = bid * 64 + (t >> 2);
        int eq  = t & 3;
        if (row >= M_ROWS) return;
        const float* hrow = hs + (size_t)row * D_IN;
        float ax = 0.f, ay = 0.f, az = 0.f, aw = 0.f;
        #pragma unroll 4
        for (int d = 0; d < D_IN; d += 4) {
            float4 h4 = *reinterpret_cast<const float4*>(hrow + d);
            float4 p0 = *reinterpret_cast<const float4*>(P + (size_t)(d + 0) * E_DIM + eq * 4);
            float4 p1 = *reinterpret_cast<const float4*>(P + (size_t)(d + 1) * E_DIM + eq * 4);
            float4 p2 = *reinterpret_cast<const float4*>(P + (size_t)(d + 2) * E_DIM + eq * 4);
            float4 p3 = *reinterpret_cast<const float4*>(P + (size_t)(d + 3) * E_DIM + eq * 4);
            ax += h4.x * p0.x + h4.y * p1.x + h4.z * p2.x + h4.w * p3.x;
            ay += h4.x * p0.y + h4.y * p1.y + h4.z * p2.y + h4.w * p3.y;
            az += h4.x * p0.z + h4.y * p1.z + h4.z * p2.z + h4.w * p3.z;
            aw += h4.x * p0.w + h4.y * p1.w + h4.z * p2.w + h4.w * p3.w;
        }
        float v[4] = {ax, ay, az, aw};
        ushort4 h, m, l;
        unsigned short* hp = (unsigned short*)&h;
        unsigned short* mp = (unsigned short*)&m;
        unsigned short* lp = (unsigned short*)&l;
        #pragma unroll
        for (int i = 0; i < 4; ++i) {
            unsigned short hb = f2bf(v[i]);      float r1 = v[i] - bf2f(hb);
            unsigned short mb = f2bf(r1);        float r2 = r1 - bf2f(mb);
            unsigned short lb = f2bf(r2);        // exact: v = h + m + l
            hp[i] = hb; mp[i] = mb; lp[i] = lb;
        }
        int rt = row >> 4, rl = row & 15;
        int g  = eq >> 1;
        int j0 = (eq & 1) * 4;
        size_t base = (size_t)rt * 512;
        *reinterpret_cast<ushort4*>(Xa + base + ((g    ) * 16 + rl) * 8 + j0) = h;
        *reinterpret_cast<ushort4*>(Xa + base + ((2 + g) * 16 + rl) * 8 + j0) = m;
        *reinterpret_cast<ushort4*>(Xb + base + ((g    ) * 16 + rl) * 8 + j0) = l;
        *reinterpret_cast<ushort4*>(Xb + base + ((2 + g) * 16 + rl) * 8 + j0) = h;
    } else {
        int bid2 = bid - 250;                     // 0..127
        int c  = bid2 * 64 + (t >> 2);
        int eq = t & 3;
        float4 v4 = *reinterpret_cast<const float4*>(CB + (size_t)c * E_DIM + eq * 4);
        float v[4] = {v4.x, v4.y, v4.z, v4.w};
        ushort4 h, m, l;
        unsigned short* hp = (unsigned short*)&h;
        unsigned short* mp = (unsigned short*)&m;
        unsigned short* lp = (unsigned short*)&l;
        #pragma unroll
        for (int i = 0; i < 4; ++i) {
            unsigned short hb = f2bf(v[i]);      float r1 = v[i] - bf2f(hb);
            unsigned short mb = f2bf(r1);        float r2 = r1 - bf2f(mb);
            unsigned short lb = f2bf(r2);
            hp[i] = hb; mp[i] = mb; lp[i] = lb;
        }
        int kt = c >> 4, cl = c & 15;
        int g  = eq >> 1;
        int j0 = (eq & 1) * 4;
        size_t base = (size_t)kt * 512;
        *reinterpret_cast<ushort4*>(CBa + base + ((g    ) * 16 + cl) * 8 + j0) = h;
        *reinterpret_cast<ushort4*>(CBa + base + ((2 + g) * 16 + cl) * 8 + j0) = m;
        *reinterpret_cast<ushort4*>(CBc + base + ((g    ) * 16 + cl) * 8 + j0) = h;
        *reinterpret_cast<ushort4*>(CBc + base + ((2 + g) * 16 + cl) * 8 + j0) = l;
    }
}

// ---------- MFMA score + fused argmax ----------
// Round-14 verified loop (3 ds_read_b128 + 3 chained MFMAs, rb-clustered XCD
// swizzle, 32 KB whole-chunk LDS staging, one barrier). Single change vs r14:
// occupancy is LDS-capped at 5 blocks/CU, so the (256,8) VGPR clamp bought
// nothing — relax to (256,5) (~96 VGPR budget) and hoist ALL A-fragment loads
// (both row-groups) BEFORE the barrier so their global latency drains under
// the staging vmcnt(0) instead of serializing after it (T14 issue-early).
__global__ __launch_bounds__(256, 5) void score_kernel(const unsigned short* __restrict__ Xa,
                                                       const unsigned short* __restrict__ Xb,
                                                       const unsigned short* __restrict__ CBa,
                                                       const unsigned short* __restrict__ CBc,
                                                       unsigned long long* __restrict__ part) {
    __shared__ unsigned short sA[KT_PER_CHUNK * 512];   // 16 KB  (h'|m')
    __shared__ unsigned short sC[KT_PER_CHUNK * 512];   // 16 KB  (h'|l')

    int t    = threadIdx.x;
    int lane = t & 63;
    int w    = t >> 6;                // 0..3
    int bid  = blockIdx.x;            // 0..2047
    int xcd  = bid & 7;
    int idx  = bid >> 3;              // 0..255
    int j    = idx & 7;
    int kc   = idx >> 3;              // 0..31
    int rb   = xcd + 8 * j;           // 0..63 (rb=63 dummy), clustered per XCD

    // Stage both B streams for the whole k-chunk (4 glds rounds each) FIRST.
    {
        const unsigned char* ga = (const unsigned char*)(CBa + (size_t)kc * KT_PER_CHUNK * 512);
        const unsigned char* gc = (const unsigned char*)(CBc + (size_t)kc * KT_PER_CHUNK * 512);
        unsigned char* la = (unsigned char*)sA;
        unsigned char* lc = (unsigned char*)sC;
        int wo = w * 1024 + lane * 16;
        #pragma unroll
        for (int q = 0; q < 4; ++q)
            __builtin_amdgcn_global_load_lds((const AS1 void*)(ga + q * 4096 + wo),
                                             (AS3 void*)(la + q * 4096 + w * 1024), 16, 0, 0);
        #pragma unroll
        for (int q = 0; q < 4; ++q)
            __builtin_amdgcn_global_load_lds((const AS1 void*)(gc + q * 4096 + wo),
                                             (AS3 void*)(lc + q * 4096 + w * 1024), 16, 0, 0);
    }

    // Issue ALL A-fragment loads now — latency overlaps the staging drain.
    bf16x8 a_hm[NGRP][RPT], a_lh[NGRP][RPT];
    #pragma unroll
    for (int g = 0; g < NGRP; ++g)
        #pragma unroll
        for (int r = 0; r < RPT; ++r) {
            int rt = rb * 16 + g * 8 + w * RPT + r;
            a_hm[g][r] = *reinterpret_cast<const bf16x8*>(Xa + ((size_t)rt * 64 + lane) * 8);
            a_lh[g][r] = *reinterpret_cast<const bf16x8*>(Xb + ((size_t)rt * 64 + lane) * 8);
        }

    __syncthreads();   // compiler emits vmcnt(0) drain: staging + A-loads done

    const bf16x8* sA8 = reinterpret_cast<const bf16x8*>(sA);
    const bf16x8* sC8 = reinterpret_cast<const bf16x8*>(sC);
    int lsw  = lane ^ 32;             // swapped-half lane for the [m'|h'] operand
    int colc = lane & 15;

    #pragma unroll
    for (int g = 0; g < NGRP; ++g) {
        int rt0 = rb * 16 + g * 8 + w * RPT;

        float best[RPT][4];
        int   bidx[RPT][4];
        #pragma unroll
        for (int r = 0; r < RPT; ++r)
            #pragma unroll
            for (int i = 0; i < 4; ++i) { best[r][i] = -3.0e38f; bidx[r][i] = 0; }

        #pragma unroll 2
        for (int kt = 0; kt < KT_PER_CHUNK; ++kt) {
            bf16x8 c1 = sA8[kt * 64 + lane];
            bf16x8 c2 = sA8[kt * 64 + lsw];
            bf16x8 c3 = sC8[kt * 64 + lane];
            #pragma unroll
            for (int r = 0; r < RPT; ++r) {
                f32x4 acc = {0.f, 0.f, 0.f, 0.f};
                acc = __builtin_amdgcn_mfma_f32_16x16x32_bf16(a_hm[g][r], c1, acc, 0, 0, 0); // hh+mm
                acc = __builtin_amdgcn_mfma_f32_16x16x32_bf16(a_hm[g][r], c2, acc, 0, 0, 0); // hm+mh
                acc = __builtin_amdgcn_mfma_f32_16x16x32_bf16(a_lh[g][r], c3, acc, 0, 0, 0); // lh+hl
                #pragma unroll
                for (int i = 0; i < 4; ++i) {
                    bool gt = acc[i] > best[r][i];
                    best[r][i] = gt ? acc[i] : best[r][i];
                    bidx[r][i] = gt ? kt     : bidx[r][i];
                }
            }
        }

        // u64-key shfl reduce over the 16 columns; 1 store per row.
        // Key = mono(score)<<32 | ~idx (verified round-2 semantics).
        #pragma unroll
        for (int r = 0; r < RPT; ++r) {
            #pragma unroll
            for (int i = 0; i < 4; ++i) {
                unsigned u    = __float_as_uint(best[r][i]);
                unsigned mono = (u & 0x80000000u) ? ~u : (u | 0x80000000u);
                unsigned kg   = (unsigned)(kc * 256 + bidx[r][i] * 16 + colc);
                unsigned long long key = ((unsigned long long)mono << 32) | (unsigned)(~kg);
                #pragma unroll
                for (int off = 1; off <= 8; off <<= 1) {
                    unsigned long long ok =
                        (((unsigned long long)(unsigned)__shfl_xor((int)(key >> 32), off, 64)) << 32) |
                        (unsigned)__shfl_xor((int)(unsigned)key, off, 64);
                    key = (ok > key) ? ok : key;
                }
                if (colc == 0) {
                    int row = (rt0 + r) * 16 + (lane >> 4) * 4 + i;
                    if (row < M_ROWS) part[(size_t)row * NCHUNK + kc] = key;
                }
            }
        }
    }
}

// ---------- Decode: reduce 32 per-chunk keys per row -> int32 index ----------
__global__ __launch_bounds__(256) void decode_kernel(const unsigned long long* __restrict__ part,
                                                     int* __restrict__ out) {
    int t    = threadIdx.x;
    int lane = t & 63;
    int wv   = t >> 6;
    int row  = blockIdx.x * 32 + wv * 8 + (lane >> 3);
    int j    = lane & 7;
    const unsigned long long* p = part + (size_t)row * NCHUNK + j * 4;
    unsigned long long k0 = p[0], k1 = p[1], k2 = p[2], k3 = p[3];
    k0 = k0 > k1 ? k0 : k1;
    k2 = k2 > k3 ? k2 : k3;
    unsigned long long key = k0 > k2 ? k0 : k2;
    #pragma unroll
    for (int off = 1; off <= 4; off <<= 1) {
        unsigned long long ok =
            (((unsigned long long)(unsigned)__shfl_xor((int)(key >> 32), off, 64)) << 32) |
            (unsigned)__shfl_xor((int)(unsigned)key, off, 64);
        key = (ok > key) ? ok : key;
    }
    if (j == 0) out[row] = (int)(~(unsigned)(key & 0xFFFFFFFFull));
}

extern "C" void kernel_launch(void* const* d_in, const int* in_sizes, int n_in,
                              void* d_out, int out_size, void* d_ws, size_t ws_size,
                              hipStream_t stream) {
    const float* hs = (const float*)d_in[0];   // [8,2000,320]
    const float* P  = (const float*)d_in[1];   // [1,320,16]
    const float* CB = (const float*)d_in[2];   // [1,8192,16]
    int* out = (int*)d_out;                    // [8,1,2000] int32

    char* ws = (char*)d_ws;
    unsigned short* Xa  = (unsigned short*)(ws + XA_OFF);
    unsigned short* Xb  = (unsigned short*)(ws + XB_OFF);
    unsigned short* CBa = (unsigned short*)(ws + CBA_OFF);
    unsigned short* CBc = (unsigned short*)(ws + CBC_OFF);
    unsigned long long* part = (unsigned long long*)(ws + PART_OFF);

    prep_kernel<<<dim3(378), dim3(256), 0, stream>>>(hs, P, CB, Xa, Xb, CBa, CBc);
    score_kernel<<<dim3(NRB * NCHUNK), dim3(256), 0, stream>>>(Xa, Xb, CBa, CBc, part);
    decode_kernel<<<dim3(M_ROWS / 32), dim3(256), 0, stream>>>(part, out);
}

// Round 17
// 54.937 us; speedup vs baseline: 1.1615x; 1.0258x over previous
//
#include <hip/hip_runtime.h>
#include <stdint.h>

// Problem constants
#define M_ROWS   16000        // B*T
#define D_IN     320
#define E_DIM    16
#define K_CB     8192
#define NCHUNK   32           // k-chunks: 16 k-tiles (256 codewords) each
#define KT_PER_CHUNK 16
#define RPT      4            // row-tiles per wave (flat; 3 LDS reads serve 12 MFMAs)
#define NRB      64           // row-blocks (16 rt each; rb=63 is dummy padding)

typedef __attribute__((ext_vector_type(8))) short bf16x8;
typedef __attribute__((ext_vector_type(4))) float f32x4;

// Workspace layout (bytes) — XA/XB padded to 1024 tiles for the dummy rb
#define XA_OFF   0u                       // [1024 tiles][64 lanes][8 bf16]  (h|m)
#define XB_OFF   1048576u                 // same shape                       (l|h)
#define CBA_OFF  2097152u                 // [512 ktiles][64 lanes][8 bf16]  (h'|m')
#define CBC_OFF  2621440u                 // same                             (h'|l')
#define PART_OFF 3145728u                 // [16000 rows][32 kc] u64 partials

#define AS1 __attribute__((address_space(1)))
#define AS3 __attribute__((address_space(3)))

__device__ __forceinline__ unsigned short f2bf(float x) {
    union { float f; unsigned u; } v; v.f = x;
    unsigned r = v.u + 0x7FFFu + ((v.u >> 16) & 1u);   // round-to-nearest-even
    return (unsigned short)(r >> 16);
}
__device__ __forceinline__ float bf2f(unsigned short b) {
    union { unsigned u; float f; } v; v.u = ((unsigned)b) << 16; return v.f;
}

// ---------- Fused prep: projection-split-pack (blocks 0..249) + codebook
// split-pack (blocks 250..377). Byte-identical to rounds 14/16. ----------
__global__ __launch_bounds__(256) void prep_kernel(const float* __restrict__ hs,
                                                   const float* __restrict__ P,
                                                   const float* __restrict__ CB,
                                                   unsigned short* __restrict__ Xa,
                                                   unsigned short* __restrict__ Xb,
                                                   unsigned short* __restrict__ CBa,
                                                   unsigned short* __restrict__ CBc) {
    int bid = blockIdx.x;
    int t   = threadIdx.x;
    if (bid < 250) {
        int row = bid * 64 + (t >> 2);
        int eq  = t & 3;
        if (row >= M_ROWS) return;
        const float* hrow = hs + (size_t)row * D_IN;
        float ax = 0.f, ay = 0.f, az = 0.f, aw = 0.f;
        #pragma unroll 4
        for (int d = 0; d < D_IN; d += 4) {
            float4 h4 = *reinterpret_cast<const float4*>(hrow + d);
            float4 p0 = *reinterpret_cast<const float4*>(P + (size_t)(d + 0) * E_DIM + eq * 4);
            float4 p1 = *reinterpret_cast<const float4*>(P + (size_t)(d + 1) * E_DIM + eq * 4);
            float4 p2 = *reinterpret_cast<const float4*>(P + (size_t)(d + 2) * E_DIM + eq * 4);
            float4 p3 = *reinterpret_cast<const float4*>(P + (size_t)(d + 3) * E_DIM + eq * 4);
            ax += h4.x * p0.x + h4.y * p1.x + h4.z * p2.x + h4.w * p3.x;
            ay += h4.x * p0.y + h4.y * p1.y + h4.z * p2.y + h4.w * p3.y;
            az += h4.x * p0.z + h4.y * p1.z + h4.z * p2.z + h4.w * p3.z;
            aw += h4.x * p0.w + h4.y * p1.w + h4.z * p2.w + h4.w * p3.w;
        }
        float v[4] = {ax, ay, az, aw};
        ushort4 h, m, l;
        unsigned short* hp = (unsigned short*)&h;
        unsigned short* mp = (unsigned short*)&m;
        unsigned short* lp = (unsigned short*)&l;
        #pragma unroll
        for (int i = 0; i < 4; ++i) {
            unsigned short hb = f2bf(v[i]);      float r1 = v[i] - bf2f(hb);
            unsigned short mb = f2bf(r1);        float r2 = r1 - bf2f(mb);
            unsigned short lb = f2bf(r2);        // exact: v = h + m + l
            hp[i] = hb; mp[i] = mb; lp[i] = lb;
        }
        int rt = row >> 4, rl = row & 15;
        int g  = eq >> 1;
        int j0 = (eq & 1) * 4;
        size_t base = (size_t)rt * 512;
        *reinterpret_cast<ushort4*>(Xa + base + ((g    ) * 16 + rl) * 8 + j0) = h;
        *reinterpret_cast<ushort4*>(Xa + base + ((2 + g) * 16 + rl) * 8 + j0) = m;
        *reinterpret_cast<ushort4*>(Xb + base + ((g    ) * 16 + rl) * 8 + j0) = l;
        *reinterpret_cast<ushort4*>(Xb + base + ((2 + g) * 16 + rl) * 8 + j0) = h;
    } else {
        int bid2 = bid - 250;                     // 0..127
        int c  = bid2 * 64 + (t >> 2);
        int eq = t & 3;
        float4 v4 = *reinterpret_cast<const float4*>(CB + (size_t)c * E_DIM + eq * 4);
        float v[4] = {v4.x, v4.y, v4.z, v4.w};
        ushort4 h, m, l;
        unsigned short* hp = (unsigned short*)&h;
        unsigned short* mp = (unsigned short*)&m;
        unsigned short* lp = (unsigned short*)&l;
        #pragma unroll
        for (int i = 0; i < 4; ++i) {
            unsigned short hb = f2bf(v[i]);      float r1 = v[i] - bf2f(hb);
            unsigned short mb = f2bf(r1);        float r2 = r1 - bf2f(mb);
            unsigned short lb = f2bf(r2);
            hp[i] = hb; mp[i] = mb; lp[i] = lb;
        }
        int kt = c >> 4, cl = c & 15;
        int g  = eq >> 1;
        int j0 = (eq & 1) * 4;
        size_t base = (size_t)kt * 512;
        *reinterpret_cast<ushort4*>(CBa + base + ((g    ) * 16 + cl) * 8 + j0) = h;
        *reinterpret_cast<ushort4*>(CBa + base + ((2 + g) * 16 + cl) * 8 + j0) = m;
        *reinterpret_cast<ushort4*>(CBc + base + ((g    ) * 16 + cl) * 8 + j0) = h;
        *reinterpret_cast<ushort4*>(CBc + base + ((2 + g) * 16 + cl) * 8 + j0) = l;
    }
}

// ---------- MFMA score + fused argmax ----------
// Best-verified pieces merged: round-10's flat RPT=4 kt-loop (3 ds_read_b128
// amortized over 12 MFMAs / 1024 scores — half the LDS traffic of the NGRP
// split), round-14's rb-clustered XCD swizzle (FETCH 9.2->5.2 MB), round-16's
// pre-barrier A-load hoist + (256,5) (occupancy is LDS-capped at 5 blocks/CU;
// VGPR budget 96 >= est. live ~88). Math byte-identical to the verified path.
__global__ __launch_bounds__(256, 5) void score_kernel(const unsigned short* __restrict__ Xa,
                                                       const unsigned short* __restrict__ Xb,
                                                       const unsigned short* __restrict__ CBa,
                                                       const unsigned short* __restrict__ CBc,
                                                       unsigned long long* __restrict__ part) {
    __shared__ unsigned short sA[KT_PER_CHUNK * 512];   // 16 KB  (h'|m')
    __shared__ unsigned short sC[KT_PER_CHUNK * 512];   // 16 KB  (h'|l')

    int t    = threadIdx.x;
    int lane = t & 63;
    int w    = t >> 6;                // 0..3
    int bid  = blockIdx.x;            // 0..2047
    int xcd  = bid & 7;
    int idx  = bid >> 3;              // 0..255
    int j    = idx & 7;
    int kc   = idx >> 3;              // 0..31
    int rb   = xcd + 8 * j;           // 0..63 (rb=63 dummy), clustered per XCD
    int rt0  = rb * 16 + w * RPT;

    // Stage both B streams for the whole k-chunk (4 glds rounds each) FIRST.
    {
        const unsigned char* ga = (const unsigned char*)(CBa + (size_t)kc * KT_PER_CHUNK * 512);
        const unsigned char* gc = (const unsigned char*)(CBc + (size_t)kc * KT_PER_CHUNK * 512);
        unsigned char* la = (unsigned char*)sA;
        unsigned char* lc = (unsigned char*)sC;
        int wo = w * 1024 + lane * 16;
        #pragma unroll
        for (int q = 0; q < 4; ++q)
            __builtin_amdgcn_global_load_lds((const AS1 void*)(ga + q * 4096 + wo),
                                             (AS3 void*)(la + q * 4096 + w * 1024), 16, 0, 0);
        #pragma unroll
        for (int q = 0; q < 4; ++q)
            __builtin_amdgcn_global_load_lds((const AS1 void*)(gc + q * 4096 + wo),
                                             (AS3 void*)(lc + q * 4096 + w * 1024), 16, 0, 0);
    }

    // Issue ALL A-fragment loads now — latency overlaps the staging drain.
    bf16x8 a_hm[RPT], a_lh[RPT];
    #pragma unroll
    for (int r = 0; r < RPT; ++r) {
        a_hm[r] = *reinterpret_cast<const bf16x8*>(Xa + ((size_t)(rt0 + r) * 64 + lane) * 8);
        a_lh[r] = *reinterpret_cast<const bf16x8*>(Xb + ((size_t)(rt0 + r) * 64 + lane) * 8);
    }

    float best[RPT][4];
    int   bidx[RPT][4];
    #pragma unroll
    for (int r = 0; r < RPT; ++r)
        #pragma unroll
        for (int i = 0; i < 4; ++i) { best[r][i] = -3.0e38f; bidx[r][i] = 0; }

    __syncthreads();   // compiler emits vmcnt(0) drain: staging + A-loads done

    const bf16x8* sA8 = reinterpret_cast<const bf16x8*>(sA);
    const bf16x8* sC8 = reinterpret_cast<const bf16x8*>(sC);
    int lsw  = lane ^ 32;             // swapped-half lane for the [m'|h'] operand
    int colc = lane & 15;

    #pragma unroll 2
    for (int kt = 0; kt < KT_PER_CHUNK; ++kt) {
        bf16x8 c1 = sA8[kt * 64 + lane];
        bf16x8 c2 = sA8[kt * 64 + lsw];
        bf16x8 c3 = sC8[kt * 64 + lane];
        #pragma unroll
        for (int r = 0; r < RPT; ++r) {
            f32x4 acc = {0.f, 0.f, 0.f, 0.f};
            acc = __builtin_amdgcn_mfma_f32_16x16x32_bf16(a_hm[r], c1, acc, 0, 0, 0); // hh+mm
            acc = __builtin_amdgcn_mfma_f32_16x16x32_bf16(a_hm[r], c2, acc, 0, 0, 0); // hm+mh
            acc = __builtin_amdgcn_mfma_f32_16x16x32_bf16(a_lh[r], c3, acc, 0, 0, 0); // lh+hl
            #pragma unroll
            for (int i = 0; i < 4; ++i) {
                bool gt = acc[i] > best[r][i];
                best[r][i] = gt ? acc[i] : best[r][i];
                bidx[r][i] = gt ? kt     : bidx[r][i];
            }
        }
    }

    // u64-key shfl reduce over the 16 columns; 1 store per row.
    // Key = mono(score)<<32 | ~idx (verified round-2 semantics).
    #pragma unroll
    for (int r = 0; r < RPT; ++r) {
        #pragma unroll
        for (int i = 0; i < 4; ++i) {
            unsigned u    = __float_as_uint(best[r][i]);
            unsigned mono = (u & 0x80000000u) ? ~u : (u | 0x80000000u);
            unsigned kg   = (unsigned)(kc * 256 + bidx[r][i] * 16 + colc);
            unsigned long long key = ((unsigned long long)mono << 32) | (unsigned)(~kg);
            #pragma unroll
            for (int off = 1; off <= 8; off <<= 1) {
                unsigned long long ok =
                    (((unsigned long long)(unsigned)__shfl_xor((int)(key >> 32), off, 64)) << 32) |
                    (unsigned)__shfl_xor((int)(unsigned)key, off, 64);
                key = (ok > key) ? ok : key;
            }
            if (colc == 0) {
                int row = (rt0 + r) * 16 + (lane >> 4) * 4 + i;
                if (row < M_ROWS) part[(size_t)row * NCHUNK + kc] = key;
            }
        }
    }
}

// ---------- Decode: reduce 32 per-chunk keys per row -> int32 index ----------
__global__ __launch_bounds__(256) void decode_kernel(const unsigned long long* __restrict__ part,
                                                     int* __restrict__ out) {
    int t    = threadIdx.x;
    int lane = t & 63;
    int wv   = t >> 6;
    int row  = blockIdx.x * 32 + wv * 8 + (lane >> 3);
    int j    = lane & 7;
    const unsigned long long* p = part + (size_t)row * NCHUNK + j * 4;
    unsigned long long k0 = p[0], k1 = p[1], k2 = p[2], k3 = p[3];
    k0 = k0 > k1 ? k0 : k1;
    k2 = k2 > k3 ? k2 : k3;
    unsigned long long key = k0 > k2 ? k0 : k2;
    #pragma unroll
    for (int off = 1; off <= 4; off <<= 1) {
        unsigned long long ok =
            (((unsigned long long)(unsigned)__shfl_xor((int)(key >> 32), off, 64)) << 32) |
            (unsigned)__shfl_xor((int)(unsigned)key, off, 64);
        key = (ok > key) ? ok : key;
    }
    if (j == 0) out[row] = (int)(~(unsigned)(key & 0xFFFFFFFFull));
}

extern "C" void kernel_launch(void* const* d_in, const int* in_sizes, int n_in,
                              void* d_out, int out_size, void* d_ws, size_t ws_size,
                              hipStream_t stream) {
    const float* hs = (const float*)d_in[0];   // [8,2000,320]
    const float* P  = (const float*)d_in[1];   // [1,320,16]
    const float* CB = (const float*)d_in[2];   // [1,8192,16]
    int* out = (int*)d_out;                    // [8,1,2000] int32

    char* ws = (char*)d_ws;
    unsigned short* Xa  = (unsigned short*)(ws + XA_OFF);
    unsigned short* Xb  = (unsigned short*)(ws + XB_OFF);
    unsigned short* CBa = (unsigned short*)(ws + CBA_OFF);
    unsigned short* CBc = (unsigned short*)(ws + CBC_OFF);
    unsigned long long* part = (unsigned long long*)(ws + PART_OFF);

    prep_kernel<<<dim3(378), dim3(256), 0, stream>>>(hs, P, CB, Xa, Xb, CBa, CBc);
    score_kernel<<<dim3(NRB * NCHUNK), dim3(256), 0, stream>>>(Xa, Xb, CBa, CBc, part);
    decode_kernel<<<dim3(M_ROWS / 32), dim3(256), 0, stream>>>(part, out);
}

// Round 18
// 53.379 us; speedup vs baseline: 1.1954x; 1.0292x over previous
//
#include <hip/hip_runtime.h>
#include <stdint.h>

// Problem constants
#define M_ROWS   16000        // B*T
#define D_IN     320
#define E_DIM    16
#define K_CB     8192
#define NCHUNK   32           // k-chunks: 16 k-tiles (256 codewords) each
#define KT_PER_CHUNK 16
#define RPT      4            // row-tiles per wave (flat; 3 LDS reads serve 12 MFMAs)
#define NRB      64           // row-blocks (16 rt each; rb=63 is dummy padding)

typedef __attribute__((ext_vector_type(8))) short bf16x8;
typedef __attribute__((ext_vector_type(4))) float f32x4;

// Workspace layout (bytes) — XA/XB padded to 1024 tiles for the dummy rb
#define XA_OFF   0u                       // [1024 tiles][64 lanes][8 bf16]  (h|m)
#define XB_OFF   1048576u                 // same shape                       (l|h)
#define CBA_OFF  2097152u                 // [512 ktiles][64 lanes][8 bf16]  (h'|m')
#define CBC_OFF  2621440u                 // same                             (h'|l')
#define KEYS_OFF 3145728u                 // [16384] u64 per-row keys

#define AS1 __attribute__((address_space(1)))
#define AS3 __attribute__((address_space(3)))

__device__ __forceinline__ unsigned short f2bf(float x) {
    union { float f; unsigned u; } v; v.f = x;
    unsigned r = v.u + 0x7FFFu + ((v.u >> 16) & 1u);   // round-to-nearest-even
    return (unsigned short)(r >> 16);
}
__device__ __forceinline__ float bf2f(unsigned short b) {
    union { unsigned u; float f; } v; v.u = ((unsigned)b) << 16; return v.f;
}

// ---------- Fused prep: projection-split-pack (blocks 0..249) + codebook
// split-pack + keys zero-init (blocks 250..377). Math identical to r14-r17. ----------
__global__ __launch_bounds__(256) void prep_kernel(const float* __restrict__ hs,
                                                   const float* __restrict__ P,
                                                   const float* __restrict__ CB,
                                                   unsigned short* __restrict__ Xa,
                                                   unsigned short* __restrict__ Xb,
                                                   unsigned short* __restrict__ CBa,
                                                   unsigned short* __restrict__ CBc,
                                                   unsigned long long* __restrict__ keys) {
    int bid = blockIdx.x;
    int t   = threadIdx.x;
    if (bid < 250) {
        int row = bid * 64 + (t >> 2);
        int eq  = t & 3;
        if (row >= M_ROWS) return;
        const float* hrow = hs + (size_t)row * D_IN;
        float ax = 0.f, ay = 0.f, az = 0.f, aw = 0.f;
        #pragma unroll 4
        for (int d = 0; d < D_IN; d += 4) {
            float4 h4 = *reinterpret_cast<const float4*>(hrow + d);
            float4 p0 = *reinterpret_cast<const float4*>(P + (size_t)(d + 0) * E_DIM + eq * 4);
            float4 p1 = *reinterpret_cast<const float4*>(P + (size_t)(d + 1) * E_DIM + eq * 4);
            float4 p2 = *reinterpret_cast<const float4*>(P + (size_t)(d + 2) * E_DIM + eq * 4);
            float4 p3 = *reinterpret_cast<const float4*>(P + (size_t)(d + 3) * E_DIM + eq * 4);
            ax += h4.x * p0.x + h4.y * p1.x + h4.z * p2.x + h4.w * p3.x;
            ay += h4.x * p0.y + h4.y * p1.y + h4.z * p2.y + h4.w * p3.y;
            az += h4.x * p0.z + h4.y * p1.z + h4.z * p2.z + h4.w * p3.z;
            aw += h4.x * p0.w + h4.y * p1.w + h4.z * p2.w + h4.w * p3.w;
        }
        float v[4] = {ax, ay, az, aw};
        ushort4 h, m, l;
        unsigned short* hp = (unsigned short*)&h;
        unsigned short* mp = (unsigned short*)&m;
        unsigned short* lp = (unsigned short*)&l;
        #pragma unroll
        for (int i = 0; i < 4; ++i) {
            unsigned short hb = f2bf(v[i]);      float r1 = v[i] - bf2f(hb);
            unsigned short mb = f2bf(r1);        float r2 = r1 - bf2f(mb);
            unsigned short lb = f2bf(r2);        // exact: v = h + m + l
            hp[i] = hb; mp[i] = mb; lp[i] = lb;
        }
        int rt = row >> 4, rl = row & 15;
        int g  = eq >> 1;
        int j0 = (eq & 1) * 4;
        size_t base = (size_t)rt * 512;
        *reinterpret_cast<ushort4*>(Xa + base + ((g    ) * 16 + rl) * 8 + j0) = h;
        *reinterpret_cast<ushort4*>(Xa + base + ((2 + g) * 16 + rl) * 8 + j0) = m;
        *reinterpret_cast<ushort4*>(Xb + base + ((g    ) * 16 + rl) * 8 + j0) = l;
        *reinterpret_cast<ushort4*>(Xb + base + ((2 + g) * 16 + rl) * 8 + j0) = h;
    } else {
        int bid2 = bid - 250;                     // 0..127
        int gid  = bid2 * 256 + t;
        if (gid < 16384) keys[gid] = 0ull;        // fused keys init (scores map to mono>0)
        int c  = bid2 * 64 + (t >> 2);
        int eq = t & 3;
        float4 v4 = *reinterpret_cast<const float4*>(CB + (size_t)c * E_DIM + eq * 4);
        float v[4] = {v4.x, v4.y, v4.z, v4.w};
        ushort4 h, m, l;
        unsigned short* hp = (unsigned short*)&h;
        unsigned short* mp = (unsigned short*)&m;
        unsigned short* lp = (unsigned short*)&l;
        #pragma unroll
        for (int i = 0; i < 4; ++i) {
            unsigned short hb = f2bf(v[i]);      float r1 = v[i] - bf2f(hb);
            unsigned short mb = f2bf(r1);        float r2 = r1 - bf2f(mb);
            unsigned short lb = f2bf(r2);
            hp[i] = hb; mp[i] = mb; lp[i] = lb;
        }
        int kt = c >> 4, cl = c & 15;
        int g  = eq >> 1;
        int j0 = (eq & 1) * 4;
        size_t base = (size_t)kt * 512;
        *reinterpret_cast<ushort4*>(CBa + base + ((g    ) * 16 + cl) * 8 + j0) = h;
        *reinterpret_cast<ushort4*>(CBa + base + ((2 + g) * 16 + cl) * 8 + j0) = m;
        *reinterpret_cast<ushort4*>(CBc + base + ((g    ) * 16 + cl) * 8 + j0) = h;
        *reinterpret_cast<ushort4*>(CBc + base + ((2 + g) * 16 + cl) * 8 + j0) = l;
    }
}

// ---------- MFMA score + fused argmax ----------
// Round-17 verified structure (flat RPT=4 kt-loop, rb-clustered XCD swizzle,
// 32 KB whole-chunk LDS staging, pre-barrier A-load hoist, (256,5)).
// Single change vs r17: cross-chunk combine via u64 atomicMax on keys[row]
// (r2-r6-verified path) — removes the 8 MB part-buffer round-trip.
__global__ __launch_bounds__(256, 5) void score_kernel(const unsigned short* __restrict__ Xa,
                                                       const unsigned short* __restrict__ Xb,
                                                       const unsigned short* __restrict__ CBa,
                                                       const unsigned short* __restrict__ CBc,
                                                       unsigned long long* __restrict__ keys) {
    __shared__ unsigned short sA[KT_PER_CHUNK * 512];   // 16 KB  (h'|m')
    __shared__ unsigned short sC[KT_PER_CHUNK * 512];   // 16 KB  (h'|l')

    int t    = threadIdx.x;
    int lane = t & 63;
    int w    = t >> 6;                // 0..3
    int bid  = blockIdx.x;            // 0..2047
    int xcd  = bid & 7;
    int idx  = bid >> 3;              // 0..255
    int j    = idx & 7;
    int kc   = idx >> 3;              // 0..31
    int rb   = xcd + 8 * j;           // 0..63 (rb=63 dummy), clustered per XCD
    int rt0  = rb * 16 + w * RPT;

    // Stage both B streams for the whole k-chunk (4 glds rounds each) FIRST.
    {
        const unsigned char* ga = (const unsigned char*)(CBa + (size_t)kc * KT_PER_CHUNK * 512);
        const unsigned char* gc = (const unsigned char*)(CBc + (size_t)kc * KT_PER_CHUNK * 512);
        unsigned char* la = (unsigned char*)sA;
        unsigned char* lc = (unsigned char*)sC;
        int wo = w * 1024 + lane * 16;
        #pragma unroll
        for (int q = 0; q < 4; ++q)
            __builtin_amdgcn_global_load_lds((const AS1 void*)(ga + q * 4096 + wo),
                                             (AS3 void*)(la + q * 4096 + w * 1024), 16, 0, 0);
        #pragma unroll
        for (int q = 0; q < 4; ++q)
            __builtin_amdgcn_global_load_lds((const AS1 void*)(gc + q * 4096 + wo),
                                             (AS3 void*)(lc + q * 4096 + w * 1024), 16, 0, 0);
    }

    // Issue ALL A-fragment loads now — latency overlaps the staging drain.
    bf16x8 a_hm[RPT], a_lh[RPT];
    #pragma unroll
    for (int r = 0; r < RPT; ++r) {
        a_hm[r] = *reinterpret_cast<const bf16x8*>(Xa + ((size_t)(rt0 + r) * 64 + lane) * 8);
        a_lh[r] = *reinterpret_cast<const bf16x8*>(Xb + ((size_t)(rt0 + r) * 64 + lane) * 8);
    }

    float best[RPT][4];
    int   bidx[RPT][4];
    #pragma unroll
    for (int r = 0; r < RPT; ++r)
        #pragma unroll
        for (int i = 0; i < 4; ++i) { best[r][i] = -3.0e38f; bidx[r][i] = 0; }

    __syncthreads();   // compiler emits vmcnt(0) drain: staging + A-loads done

    const bf16x8* sA8 = reinterpret_cast<const bf16x8*>(sA);
    const bf16x8* sC8 = reinterpret_cast<const bf16x8*>(sC);
    int lsw  = lane ^ 32;             // swapped-half lane for the [m'|h'] operand
    int colc = lane & 15;

    #pragma unroll 2
    for (int kt = 0; kt < KT_PER_CHUNK; ++kt) {
        bf16x8 c1 = sA8[kt * 64 + lane];
        bf16x8 c2 = sA8[kt * 64 + lsw];
        bf16x8 c3 = sC8[kt * 64 + lane];
        #pragma unroll
        for (int r = 0; r < RPT; ++r) {
            f32x4 acc = {0.f, 0.f, 0.f, 0.f};
            acc = __builtin_amdgcn_mfma_f32_16x16x32_bf16(a_hm[r], c1, acc, 0, 0, 0); // hh+mm
            acc = __builtin_amdgcn_mfma_f32_16x16x32_bf16(a_hm[r], c2, acc, 0, 0, 0); // hm+mh
            acc = __builtin_amdgcn_mfma_f32_16x16x32_bf16(a_lh[r], c3, acc, 0, 0, 0); // lh+hl
            #pragma unroll
            for (int i = 0; i < 4; ++i) {
                bool gt = acc[i] > best[r][i];
                best[r][i] = gt ? acc[i] : best[r][i];
                bidx[r][i] = gt ? kt     : bidx[r][i];
            }
        }
    }

    // u64-key shfl reduce over the 16 columns; one atomicMax per row.
    // Key = mono(score)<<32 | ~idx : max => higher score, then lower index on
    // ties (bitwise-identical to the verified round-2 semantics).
    #pragma unroll
    for (int r = 0; r < RPT; ++r) {
        #pragma unroll
        for (int i = 0; i < 4; ++i) {
            unsigned u    = __float_as_uint(best[r][i]);
            unsigned mono = (u & 0x80000000u) ? ~u : (u | 0x80000000u);
            unsigned kg   = (unsigned)(kc * 256 + bidx[r][i] * 16 + colc);
            unsigned long long key = ((unsigned long long)mono << 32) | (unsigned)(~kg);
            #pragma unroll
            for (int off = 1; off <= 8; off <<= 1) {
                unsigned long long ok =
                    (((unsigned long long)(unsigned)__shfl_xor((int)(key >> 32), off, 64)) << 32) |
                    (unsigned)__shfl_xor((int)(unsigned)key, off, 64);
                key = (ok > key) ? ok : key;
            }
            if (colc == 0) {
                int row = (rt0 + r) * 16 + (lane >> 4) * 4 + i;
                if (row < M_ROWS) atomicMax(keys + row, key);
            }
        }
    }
}

// ---------- Decode: keys -> int32 indices (elementwise) ----------
__global__ __launch_bounds__(256) void decode_kernel(const unsigned long long* __restrict__ keys,
                                                     int* __restrict__ out) {
    int i = blockIdx.x * 256 + threadIdx.x;
    if (i < M_ROWS) out[i] = (int)(~(unsigned)(keys[i] & 0xFFFFFFFFull));
}

extern "C" void kernel_launch(void* const* d_in, const int* in_sizes, int n_in,
                              void* d_out, int out_size, void* d_ws, size_t ws_size,
                              hipStream_t stream) {
    const float* hs = (const float*)d_in[0];   // [8,2000,320]
    const float* P  = (const float*)d_in[1];   // [1,320,16]
    const float* CB = (const float*)d_in[2];   // [1,8192,16]
    int* out = (int*)d_out;                    // [8,1,2000] int32

    char* ws = (char*)d_ws;
    unsigned short* Xa  = (unsigned short*)(ws + XA_OFF);
    unsigned short* Xb  = (unsigned short*)(ws + XB_OFF);
    unsigned short* CBa = (unsigned short*)(ws + CBA_OFF);
    unsigned short* CBc = (unsigned short*)(ws + CBC_OFF);
    unsigned long long* keys = (unsigned long long*)(ws + KEYS_OFF);

    prep_kernel<<<dim3(378), dim3(256), 0, stream>>>(hs, P, CB, Xa, Xb, CBa, CBc, keys);
    score_kernel<<<dim3(NRB * NCHUNK), dim3(256), 0, stream>>>(Xa, Xb, CBa, CBc, keys);
    decode_kernel<<<dim3(63), dim3(256), 0, stream>>>(keys, out);
}